// Round 7
// baseline (670.566 us; speedup 1.0000x reference)
//
#include <hip/hip_runtime.h>
#include <hip/hip_bf16.h>
#include <stdint.h>

#define DIN   4096
#define DOUT  4096
#define MTOT  8192

#define BK64   64
#define NKT    (DIN / BK64)   // 64 K-tiles

typedef float f32x4  __attribute__((ext_vector_type(4)));
typedef short bf16x8 __attribute__((ext_vector_type(8)));

__device__ __forceinline__ ushort f2bf(float f) {
  __hip_bfloat16 h = __float2bfloat16(f);  // RNE
  ushort r;
  __builtin_memcpy(&r, &h, sizeof(r));
  return r;
}

__device__ __forceinline__ void glds16(const void* g, void* l) {
  __builtin_amdgcn_global_load_lds(
      (__attribute__((address_space(1))) void*)g,
      (__attribute__((address_space(3))) void*)l, 16, 0, 0);
}

// ---------------------------------------------------------------------------
// Kernel 1: per-row alpha (fp64 accumulate) + ternary quantize -> bf16
// ---------------------------------------------------------------------------
__global__ __launch_bounds__(256) void quant_kernel(const float* __restrict__ W,
                                                    ushort* __restrict__ QW) {
  const int row = blockIdx.x;
  const int t = threadIdx.x;
  const float* wr = W + (size_t)row * DIN;

  float4 v[4];
  double s = 0.0;
#pragma unroll
  for (int j = 0; j < 4; ++j) {
    v[j] = reinterpret_cast<const float4*>(wr)[j * 256 + t];
    s += (double)fabsf(v[j].x) + (double)fabsf(v[j].y) +
         (double)fabsf(v[j].z) + (double)fabsf(v[j].w);
  }
#pragma unroll
  for (int off = 32; off > 0; off >>= 1) s += __shfl_down(s, off, 64);

  __shared__ double ssum[4];
  __shared__ float salpha;
  if ((t & 63) == 0) ssum[t >> 6] = s;
  __syncthreads();
  if (t == 0) salpha = (float)((ssum[0] + ssum[1] + ssum[2] + ssum[3]) / (double)DIN);
  __syncthreads();
  const float alpha = salpha;

  ushort4* qo = reinterpret_cast<ushort4*>(QW + (size_t)row * DIN);
#pragma unroll
  for (int j = 0; j < 4; ++j) {
    ushort4 q;
    q.x = v[j].x > alpha ? 0x3F80 : (v[j].x < -alpha ? 0xBF80 : 0);
    q.y = v[j].y > alpha ? 0x3F80 : (v[j].y < -alpha ? 0xBF80 : 0);
    q.z = v[j].z > alpha ? 0x3F80 : (v[j].z < -alpha ? 0xBF80 : 0);
    q.w = v[j].w > alpha ? 0x3F80 : (v[j].w < -alpha ? 0xBF80 : 0);
    qo[j * 256 + t] = q;
  }
}

// ---------------------------------------------------------------------------
// Kernel 2: x fp32 -> bf16
// ---------------------------------------------------------------------------
__global__ __launch_bounds__(256) void cvt_kernel(const float* __restrict__ X,
                                                  ushort* __restrict__ XB, int n4) {
  int idx = blockIdx.x * 256 + threadIdx.x;
  const int stride = gridDim.x * 256;
  for (int i = idx; i < n4; i += stride) {
    float4 v = reinterpret_cast<const float4*>(X)[i];
    ushort4 o;
    o.x = f2bf(v.x); o.y = f2bf(v.y); o.z = f2bf(v.z); o.w = f2bf(v.w);
    reinterpret_cast<ushort4*>(XB)[i] = o;
  }
}

// ---------------------------------------------------------------------------
// Kernel 3: 256x256 8-phase bf16 MFMA GEMM, round-7 "v7" schedule.
// Quadrants (0,0),(1,0),(1,1),(0,1). Reads 8/8/0/8; staging 1 half-tile per
// phase (m201-style even distribution); full next-tile B read at ph4 after
// the vmcnt+barrier proves it landed.
//
//   ph1: read aA(T)[8];  stage B.h0(T+2); BAR; lgkm0; MMA(0,0)=aA*b0c; BAR
//   ph2: read aB(T)[8];  stage B.h1(T+2); BAR; lgkm0; MMA(1,0)=aB*b0c; BAR
//   ph3: (no reads)      stage A.h0(T+2); BAR; lgkm0; MMA(1,1)=aB*b1c; BAR
//   ph4: stage A.h1(T+2); vmcnt(8); BAR; lgkm0; read bALL(T+1)[8];
//        MMA(0,1)=aA*b1c; lgkm0; BAR
//
// Region/overwrite audit (staged halves are row-ranges; a wave reads b0 AND
// b1 from ONE staged B-half, aA AND aB from ONE staged A-half):
//   B(T+2)->Bs[buf] staged ph1/ph2: ALL reads of Bs[buf] (full bALL(T))
//     happened at (T-1).ph4 and drained at its trailing lgkm0 before that
//     phase's BAR2, which every wave crossed before reaching T.ph1.  SAFE.
//   A(T+2)->As[buf] staged ph3/ph4: aA drained at T.ph1's lgkm0, aB at
//     T.ph2's lgkm0, both before the respective BAR2.                 SAFE.
//   bALL(T+1) reads Bs[buf^1]: staged during T-1 (ph1/ph2), landed by
//     T.ph4's vmcnt(8)+BAR1; region next overwritten at (T+1).ph1/ph2,
//     after these reads drain at T.ph4's trailing lgkm0 + BAR2.       SAFE.
// vmcnt ledger (per-tile issue order B0,B1,A0,A1; prologue mirrors it):
//   at T.ph4's wait, exactly the 8 loads of tile T+2 trail tile T+1's last
//   load -> vmcnt(8) == tile T+1 fully landed. vmcnt(0) for T >= NKT-2
//   (no T+2 issues happen then, so the in-flight count collapses).
// ---------------------------------------------------------------------------
__global__ __launch_bounds__(512, 2) void gemm256_kernel(
    const ushort* __restrict__ XB, const ushort* __restrict__ QW,
    const float* __restrict__ scale, const float* __restrict__ bias,
    float* __restrict__ out) {
  __shared__ ushort As[2][16384];  // 32 KB each buf
  __shared__ ushort Bs[2][16384];

  const int t = threadIdx.x;
  const int lane = t & 63;
  const int wid = t >> 6;
  const int wr = wid >> 2, wc = wid & 3;          // 2x4 wave grid

  // XCD-bijective block swizzle: 512 wgs, 8 XCDs, 64 wgs/XCD chunk.
  // XCD k owns swz in [k*64,(k+1)*64) -> n-idx {2k,2k+1} x all 32 m-idx:
  // B-panels L2-resident per XCD.
  const int wg = blockIdx.x;                       // 0..511
  const int swz = (wg & 7) * 64 + (wg >> 3);
  const int m0 = (swz & 31) * 256;
  const int n0 = (swz >> 5) * 256;

  const ushort* ag = XB + (size_t)m0 * DIN;
  const ushort* bg = QW + (size_t)n0 * DIN;

  f32x4 acc[8][4] = {};            // [m-frag 0..7][n-frag 0..3]
  bf16x8 aA[4][2], aB[4][2];       // A halves mh=0 / mh=1
  bf16x8 bA[4][2], bB[4][2];       // full B set (4 n-frags), tile-parity dbuf

  const int r = lane & 15, kq = lane >> 4;
  const int srow = t >> 3;                         // 0..63
  const int srcc = ((t & 7) ^ ((t >> 3) & 7)) * 8; // inverse-swizzled src chunk (elems)

// issue one half-tile: tile Tt, q: 0=A.h0 1=B.h0 2=A.h1 3=B.h1
#define ISSUE_H(Tt_, q_) do {                                                   \
    const int T_ = (Tt_);                                                       \
    if (T_ < NKT) {                                                             \
      const int q__ = (q_), hf_ = q__ >> 1, bf_ = T_ & 1;                       \
      const ushort* gb_ = (q__ & 1) ? bg : ag;                                  \
      ushort* lb_ = (q__ & 1) ? &Bs[bf_][0] : &As[bf_][0];                      \
      glds16(gb_ + (size_t)(hf_ * 128 + srow) * DIN + T_ * 64 + srcc,           \
             lb_ + hf_ * 8192 + t * 8);                                         \
      glds16(gb_ + (size_t)(hf_ * 128 + 64 + srow) * DIN + T_ * 64 + srcc,      \
             lb_ + hf_ * 8192 + 4096 + t * 8);                                  \
    }                                                                           \
  } while (0)

#define READA_TO(dst_, buf_, mh_) do {                                          \
    _Pragma("unroll")                                                           \
    for (int mi = 0; mi < 4; ++mi) {                                            \
      const int row_ = wr * 128 + ((mh_) * 4 + mi) * 16 + r;                    \
      dst_[mi][0] = *reinterpret_cast<const bf16x8*>(                           \
          &As[buf_][row_ * 64 + ((0 + kq) ^ (r & 7)) * 8]);                     \
      dst_[mi][1] = *reinterpret_cast<const bf16x8*>(                           \
          &As[buf_][row_ * 64 + ((4 + kq) ^ (r & 7)) * 8]);                     \
    }                                                                           \
  } while (0)

// read ALL 4 B n-frags of one tile
#define READBALL(dst_, buf_) do {                                               \
    _Pragma("unroll")                                                           \
    for (int ni = 0; ni < 4; ++ni) {                                            \
      const int row_ = wc * 64 + ni * 16 + r;                                   \
      dst_[ni][0] = *reinterpret_cast<const bf16x8*>(                           \
          &Bs[buf_][row_ * 64 + ((0 + kq) ^ (r & 7)) * 8]);                     \
      dst_[ni][1] = *reinterpret_cast<const bf16x8*>(                           \
          &Bs[buf_][row_ * 64 + ((4 + kq) ^ (r & 7)) * 8]);                     \
    }                                                                           \
  } while (0)

// breg_ is a full [4][2] B set; nh selects frag pair {nh*2, nh*2+1}
#define MMA(mh_, nh_, areg_, breg_) do {                                        \
    __builtin_amdgcn_s_setprio(1);                                              \
    _Pragma("unroll")                                                           \
    for (int mi = 0; mi < 4; ++mi) {                                            \
      _Pragma("unroll")                                                         \
      for (int ni = 0; ni < 2; ++ni) {                                          \
        acc[(mh_) * 4 + mi][(nh_) * 2 + ni] =                                   \
            __builtin_amdgcn_mfma_f32_16x16x32_bf16(                            \
                areg_[mi][0], breg_[(nh_) * 2 + ni][0],                         \
                acc[(mh_) * 4 + mi][(nh_) * 2 + ni], 0, 0, 0);                  \
        acc[(mh_) * 4 + mi][(nh_) * 2 + ni] =                                   \
            __builtin_amdgcn_mfma_f32_16x16x32_bf16(                            \
                areg_[mi][1], breg_[(nh_) * 2 + ni][1],                         \
                acc[(mh_) * 4 + mi][(nh_) * 2 + ni], 0, 0, 0);                  \
      }                                                                         \
    }                                                                           \
    __builtin_amdgcn_s_setprio(0);                                              \
  } while (0)

#define BAR() __builtin_amdgcn_s_barrier()
#define LGKM0() asm volatile("s_waitcnt lgkmcnt(0)" ::: "memory")

// one K-tile: buf_ = T&1 (compile-time), bc_ = this tile's B set, bn_ = next's
#define TILE(T_, buf_, bc_, bn_) do {                                           \
    /* ph1: (0,0) */                                                            \
    READA_TO(aA, buf_, 0);                                                      \
    ISSUE_H((T_) + 2, 1);                                                       \
    BAR(); LGKM0();                                                             \
    MMA(0, 0, aA, bc_);                                                         \
    BAR();                                                                      \
    /* ph2: (1,0) */                                                            \
    READA_TO(aB, buf_, 1);                                                      \
    ISSUE_H((T_) + 2, 3);                                                       \
    BAR(); LGKM0();                                                             \
    MMA(1, 0, aB, bc_);                                                         \
    BAR();                                                                      \
    /* ph3: (1,1) — pure-MFMA phase, no reads */                                \
    ISSUE_H((T_) + 2, 0);                                                       \
    BAR(); LGKM0();                                                             \
    MMA(1, 1, aB, bc_);                                                         \
    BAR();                                                                      \
    /* ph4: (0,1) */                                                            \
    ISSUE_H((T_) + 2, 2);                                                       \
    if ((T_) < NKT - 2)                                                         \
      asm volatile("s_waitcnt vmcnt(8)" ::: "memory");                          \
    else                                                                        \
      asm volatile("s_waitcnt vmcnt(0)" ::: "memory");                          \
    BAR(); LGKM0();                                                             \
    if ((T_) + 1 < NKT) { READBALL(bn_, (buf_) ^ 1); }                          \
    MMA(0, 1, aA, bc_);                                                         \
    LGKM0();  /* drain bn reads before BAR2: overwrite-safety anchor */         \
    BAR();                                                                      \
  } while (0)

  // prologue: tiles 0 and 1, per-tile issue order B0,B1,A0,A1 (16 loads),
  // matching the steady-state stream order for the vmcnt ledger.
  ISSUE_H(0, 1); ISSUE_H(0, 3); ISSUE_H(0, 0); ISSUE_H(0, 2);
  ISSUE_H(1, 1); ISSUE_H(1, 3); ISSUE_H(1, 0); ISSUE_H(1, 2);
  asm volatile("s_waitcnt vmcnt(8)" ::: "memory");  // tile 0 fully landed
  __builtin_amdgcn_s_barrier();
  READBALL(bA, 0);       // full B of tile 0
  LGKM0();               // drain before any wave can issue B(2) at T0.ph1
  __builtin_amdgcn_s_barrier();

  for (int T = 0; T < NKT; T += 2) {
    TILE(T, 0, bA, bB);
    TILE(T + 1, 1, bB, bA);
  }

  // epilogue: C/D lane map col=lane&15, row=(lane>>4)*4+e (m89-verified)
  const int q4 = lane >> 4;
#pragma unroll
  for (int ni = 0; ni < 4; ++ni) {
    const int col = n0 + wc * 64 + ni * 16 + r;
    const float sc = scale[col];
    const float bs = bias[col];
#pragma unroll
    for (int mi = 0; mi < 8; ++mi) {
      const int row = m0 + wr * 128 + mi * 16 + q4 * 4;
#pragma unroll
      for (int e = 0; e < 4; ++e)
        out[(size_t)(row + e) * DOUT + col] = acc[mi][ni][e] * sc + bs;
    }
  }
#undef ISSUE_H
#undef READA_TO
#undef READBALL
#undef MMA
#undef BAR
#undef LGKM0
#undef TILE
}

extern "C" void kernel_launch(void* const* d_in, const int* in_sizes, int n_in,
                              void* d_out, int out_size, void* d_ws, size_t ws_size,
                              hipStream_t stream) {
  const float* X     = (const float*)d_in[0];
  const float* W     = (const float*)d_in[1];
  const float* scale = (const float*)d_in[2];
  const float* bias  = (const float*)d_in[3];
  float* out = (float*)d_out;

  const size_t qw_bytes = (size_t)DOUT * DIN * sizeof(ushort);  // 32 MB
  ushort* QW = (ushort*)d_ws;
  ushort* XB = (ushort*)((char*)d_ws + qw_bytes);

  quant_kernel<<<DOUT, 256, 0, stream>>>(W, QW);
  cvt_kernel<<<2048, 256, 0, stream>>>(X, XB, MTOT * DIN / 4);
  gemm256_kernel<<<512, 512, 0, stream>>>(XB, QW, scale, bias, out);
}

// Round 8
// 569.391 us; speedup vs baseline: 1.1777x; 1.1777x over previous
//
#include <hip/hip_runtime.h>
#include <hip/hip_bf16.h>
#include <stdint.h>

#define DIN   4096
#define DOUT  4096
#define MTOT  8192

#define BK64   64
#define NKT    (DIN / BK64)   // 64 K-tiles

typedef float f32x4  __attribute__((ext_vector_type(4)));
typedef short bf16x8 __attribute__((ext_vector_type(8)));

__device__ __forceinline__ ushort f2bf(float f) {
  __hip_bfloat16 h = __float2bfloat16(f);  // RNE
  ushort r;
  __builtin_memcpy(&r, &h, sizeof(r));
  return r;
}

__device__ __forceinline__ void glds16(const void* g, void* l) {
  __builtin_amdgcn_global_load_lds(
      (__attribute__((address_space(1))) void*)g,
      (__attribute__((address_space(3))) void*)l, 16, 0, 0);
}

// ---------------------------------------------------------------------------
// Kernel 1: per-row alpha (fp64 accumulate) + ternary quantize -> bf16
// ---------------------------------------------------------------------------
__global__ __launch_bounds__(256) void quant_kernel(const float* __restrict__ W,
                                                    ushort* __restrict__ QW) {
  const int row = blockIdx.x;
  const int t = threadIdx.x;
  const float* wr = W + (size_t)row * DIN;

  float4 v[4];
  double s = 0.0;
#pragma unroll
  for (int j = 0; j < 4; ++j) {
    v[j] = reinterpret_cast<const float4*>(wr)[j * 256 + t];
    s += (double)fabsf(v[j].x) + (double)fabsf(v[j].y) +
         (double)fabsf(v[j].z) + (double)fabsf(v[j].w);
  }
#pragma unroll
  for (int off = 32; off > 0; off >>= 1) s += __shfl_down(s, off, 64);

  __shared__ double ssum[4];
  __shared__ float salpha;
  if ((t & 63) == 0) ssum[t >> 6] = s;
  __syncthreads();
  if (t == 0) salpha = (float)((ssum[0] + ssum[1] + ssum[2] + ssum[3]) / (double)DIN);
  __syncthreads();
  const float alpha = salpha;

  ushort4* qo = reinterpret_cast<ushort4*>(QW + (size_t)row * DIN);
#pragma unroll
  for (int j = 0; j < 4; ++j) {
    ushort4 q;
    q.x = v[j].x > alpha ? 0x3F80 : (v[j].x < -alpha ? 0xBF80 : 0);
    q.y = v[j].y > alpha ? 0x3F80 : (v[j].y < -alpha ? 0xBF80 : 0);
    q.z = v[j].z > alpha ? 0x3F80 : (v[j].z < -alpha ? 0xBF80 : 0);
    q.w = v[j].w > alpha ? 0x3F80 : (v[j].w < -alpha ? 0xBF80 : 0);
    qo[j * 256 + t] = q;
  }
}

// ---------------------------------------------------------------------------
// Kernel 2: x fp32 -> bf16
// ---------------------------------------------------------------------------
__global__ __launch_bounds__(256) void cvt_kernel(const float* __restrict__ X,
                                                  ushort* __restrict__ XB, int n4) {
  int idx = blockIdx.x * 256 + threadIdx.x;
  const int stride = gridDim.x * 256;
  for (int i = idx; i < n4; i += stride) {
    float4 v = reinterpret_cast<const float4*>(X)[i];
    ushort4 o;
    o.x = f2bf(v.x); o.y = f2bf(v.y); o.z = f2bf(v.z); o.w = f2bf(v.w);
    reinterpret_cast<ushort4*>(XB)[i] = o;
  }
}

// ---------------------------------------------------------------------------
// Kernel 3: 256x256 8-phase bf16 MFMA GEMM, round-8 = v7 schedule + plain 2D
// grid (round-7 post-mortem: XCD swizzle destroyed A-locality; FETCH 3.8x).
// Quadrants (0,0),(1,0),(1,1),(0,1). Reads 8/8/0/8; staging 1 half-tile per
// phase; full next-tile B read at ph4 after the vmcnt+barrier proves it
// landed.
//
//   ph1: read aA(T)[8];  stage B.h0(T+2); BAR; lgkm0; MMA(0,0)=aA*b0c; BAR
//   ph2: read aB(T)[8];  stage B.h1(T+2); BAR; lgkm0; MMA(1,0)=aB*b0c; BAR
//   ph3: (no reads)      stage A.h0(T+2); BAR; lgkm0; MMA(1,1)=aB*b1c; BAR
//   ph4: stage A.h1(T+2); vmcnt(8); BAR; lgkm0; read bALL(T+1)[8];
//        MMA(0,1)=aA*b1c; lgkm0; BAR
//
// Region/overwrite audit (staged halves are row-ranges; a wave reads b0 AND
// b1 from ONE staged B-half, aA AND aB from ONE staged A-half):
//   B(T+2)->Bs[buf] staged ph1/ph2: ALL reads of Bs[buf] (full bALL(T))
//     happened at (T-1).ph4 and drained at its trailing lgkm0 before that
//     phase's BAR2, which every wave crossed before reaching T.ph1.  SAFE.
//   A(T+2)->As[buf] staged ph3/ph4: aA drained at T.ph1's lgkm0, aB at
//     T.ph2's lgkm0, both before the respective BAR2.                 SAFE.
//   bALL(T+1) reads Bs[buf^1]: staged during T-1 (ph1/ph2), landed by
//     T.ph4's vmcnt(8)+BAR1; region next overwritten at (T+1).ph1/ph2,
//     after these reads drain at T.ph4's trailing lgkm0 + BAR2.       SAFE.
// vmcnt ledger (per-tile issue order B0,B1,A0,A1; prologue mirrors it):
//   at T.ph4's wait, exactly the 8 loads of tile T+2 trail tile T+1's last
//   load -> vmcnt(8) == tile T+1 fully landed. vmcnt(0) for T >= NKT-2.
// ---------------------------------------------------------------------------
__global__ __launch_bounds__(512, 2) void gemm256_kernel(
    const ushort* __restrict__ XB, const ushort* __restrict__ QW,
    const float* __restrict__ scale, const float* __restrict__ bias,
    float* __restrict__ out) {
  __shared__ ushort As[2][16384];  // 32 KB each buf
  __shared__ ushort Bs[2][16384];

  const int t = threadIdx.x;
  const int lane = t & 63;
  const int wid = t >> 6;
  const int wr = wid >> 2, wc = wid & 3;          // 2x4 wave grid
  const int m0 = blockIdx.x * 256;                // m fast-varying (r6 layout)
  const int n0 = blockIdx.y * 256;

  const ushort* ag = XB + (size_t)m0 * DIN;
  const ushort* bg = QW + (size_t)n0 * DIN;

  f32x4 acc[8][4] = {};            // [m-frag 0..7][n-frag 0..3]
  bf16x8 aA[4][2], aB[4][2];       // A halves mh=0 / mh=1
  bf16x8 bA[4][2], bB[4][2];       // full B set (4 n-frags), tile-parity dbuf

  const int r = lane & 15, kq = lane >> 4;
  const int srow = t >> 3;                         // 0..63
  const int srcc = ((t & 7) ^ ((t >> 3) & 7)) * 8; // inverse-swizzled src chunk (elems)

// issue one half-tile: tile Tt, q: 0=A.h0 1=B.h0 2=A.h1 3=B.h1
#define ISSUE_H(Tt_, q_) do {                                                   \
    const int T_ = (Tt_);                                                       \
    if (T_ < NKT) {                                                             \
      const int q__ = (q_), hf_ = q__ >> 1, bf_ = T_ & 1;                       \
      const ushort* gb_ = (q__ & 1) ? bg : ag;                                  \
      ushort* lb_ = (q__ & 1) ? &Bs[bf_][0] : &As[bf_][0];                      \
      glds16(gb_ + (size_t)(hf_ * 128 + srow) * DIN + T_ * 64 + srcc,           \
             lb_ + hf_ * 8192 + t * 8);                                         \
      glds16(gb_ + (size_t)(hf_ * 128 + 64 + srow) * DIN + T_ * 64 + srcc,      \
             lb_ + hf_ * 8192 + 4096 + t * 8);                                  \
    }                                                                           \
  } while (0)

#define READA_TO(dst_, buf_, mh_) do {                                          \
    _Pragma("unroll")                                                           \
    for (int mi = 0; mi < 4; ++mi) {                                            \
      const int row_ = wr * 128 + ((mh_) * 4 + mi) * 16 + r;                    \
      dst_[mi][0] = *reinterpret_cast<const bf16x8*>(                           \
          &As[buf_][row_ * 64 + ((0 + kq) ^ (r & 7)) * 8]);                     \
      dst_[mi][1] = *reinterpret_cast<const bf16x8*>(                           \
          &As[buf_][row_ * 64 + ((4 + kq) ^ (r & 7)) * 8]);                     \
    }                                                                           \
  } while (0)

// read ALL 4 B n-frags of one tile
#define READBALL(dst_, buf_) do {                                               \
    _Pragma("unroll")                                                           \
    for (int ni = 0; ni < 4; ++ni) {                                            \
      const int row_ = wc * 64 + ni * 16 + r;                                   \
      dst_[ni][0] = *reinterpret_cast<const bf16x8*>(                           \
          &Bs[buf_][row_ * 64 + ((0 + kq) ^ (r & 7)) * 8]);                     \
      dst_[ni][1] = *reinterpret_cast<const bf16x8*>(                           \
          &Bs[buf_][row_ * 64 + ((4 + kq) ^ (r & 7)) * 8]);                     \
    }                                                                           \
  } while (0)

// breg_ is a full [4][2] B set; nh selects frag pair {nh*2, nh*2+1}
#define MMA(mh_, nh_, areg_, breg_) do {                                        \
    __builtin_amdgcn_s_setprio(1);                                              \
    _Pragma("unroll")                                                           \
    for (int mi = 0; mi < 4; ++mi) {                                            \
      _Pragma("unroll")                                                         \
      for (int ni = 0; ni < 2; ++ni) {                                          \
        acc[(mh_) * 4 + mi][(nh_) * 2 + ni] =                                   \
            __builtin_amdgcn_mfma_f32_16x16x32_bf16(                            \
                areg_[mi][0], breg_[(nh_) * 2 + ni][0],                         \
                acc[(mh_) * 4 + mi][(nh_) * 2 + ni], 0, 0, 0);                  \
        acc[(mh_) * 4 + mi][(nh_) * 2 + ni] =                                   \
            __builtin_amdgcn_mfma_f32_16x16x32_bf16(                            \
                areg_[mi][1], breg_[(nh_) * 2 + ni][1],                         \
                acc[(mh_) * 4 + mi][(nh_) * 2 + ni], 0, 0, 0);                  \
      }                                                                         \
    }                                                                           \
    __builtin_amdgcn_s_setprio(0);                                              \
  } while (0)

#define BAR() __builtin_amdgcn_s_barrier()
#define LGKM0() asm volatile("s_waitcnt lgkmcnt(0)" ::: "memory")

// one K-tile: buf_ = T&1 (compile-time), bc_ = this tile's B set, bn_ = next's
#define TILE(T_, buf_, bc_, bn_) do {                                           \
    /* ph1: (0,0) */                                                            \
    READA_TO(aA, buf_, 0);                                                      \
    ISSUE_H((T_) + 2, 1);                                                       \
    BAR(); LGKM0();                                                             \
    MMA(0, 0, aA, bc_);                                                         \
    BAR();                                                                      \
    /* ph2: (1,0) */                                                            \
    READA_TO(aB, buf_, 1);                                                      \
    ISSUE_H((T_) + 2, 3);                                                       \
    BAR(); LGKM0();                                                             \
    MMA(1, 0, aB, bc_);                                                         \
    BAR();                                                                      \
    /* ph3: (1,1) — pure-MFMA phase, no reads */                                \
    ISSUE_H((T_) + 2, 0);                                                       \
    BAR(); LGKM0();                                                             \
    MMA(1, 1, aB, bc_);                                                         \
    BAR();                                                                      \
    /* ph4: (0,1) */                                                            \
    ISSUE_H((T_) + 2, 2);                                                       \
    if ((T_) < NKT - 2)                                                         \
      asm volatile("s_waitcnt vmcnt(8)" ::: "memory");                          \
    else                                                                        \
      asm volatile("s_waitcnt vmcnt(0)" ::: "memory");                          \
    BAR(); LGKM0();                                                             \
    if ((T_) + 1 < NKT) { READBALL(bn_, (buf_) ^ 1); }                          \
    MMA(0, 1, aA, bc_);                                                         \
    LGKM0();  /* drain bn reads before BAR2: overwrite-safety anchor */         \
    BAR();                                                                      \
  } while (0)

  // prologue: tiles 0 and 1, per-tile issue order B0,B1,A0,A1 (16 loads),
  // matching the steady-state stream order for the vmcnt ledger.
  ISSUE_H(0, 1); ISSUE_H(0, 3); ISSUE_H(0, 0); ISSUE_H(0, 2);
  ISSUE_H(1, 1); ISSUE_H(1, 3); ISSUE_H(1, 0); ISSUE_H(1, 2);
  asm volatile("s_waitcnt vmcnt(8)" ::: "memory");  // tile 0 fully landed
  __builtin_amdgcn_s_barrier();
  READBALL(bA, 0);       // full B of tile 0
  LGKM0();               // drain before any wave can issue B(2) at T0.ph1
  __builtin_amdgcn_s_barrier();

  for (int T = 0; T < NKT; T += 2) {
    TILE(T, 0, bA, bB);
    TILE(T + 1, 1, bB, bA);
  }

  // epilogue: C/D lane map col=lane&15, row=(lane>>4)*4+e (m89-verified)
  const int q4 = lane >> 4;
#pragma unroll
  for (int ni = 0; ni < 4; ++ni) {
    const int col = n0 + wc * 64 + ni * 16 + r;
    const float sc = scale[col];
    const float bs = bias[col];
#pragma unroll
    for (int mi = 0; mi < 8; ++mi) {
      const int row = m0 + wr * 128 + mi * 16 + q4 * 4;
#pragma unroll
      for (int e = 0; e < 4; ++e)
        out[(size_t)(row + e) * DOUT + col] = acc[mi][ni][e] * sc + bs;
    }
  }
#undef ISSUE_H
#undef READA_TO
#undef READBALL
#undef MMA
#undef BAR
#undef LGKM0
#undef TILE
}

extern "C" void kernel_launch(void* const* d_in, const int* in_sizes, int n_in,
                              void* d_out, int out_size, void* d_ws, size_t ws_size,
                              hipStream_t stream) {
  const float* X     = (const float*)d_in[0];
  const float* W     = (const float*)d_in[1];
  const float* scale = (const float*)d_in[2];
  const float* bias  = (const float*)d_in[3];
  float* out = (float*)d_out;

  const size_t qw_bytes = (size_t)DOUT * DIN * sizeof(ushort);  // 32 MB
  ushort* QW = (ushort*)d_ws;
  ushort* XB = (ushort*)((char*)d_ws + qw_bytes);

  quant_kernel<<<DOUT, 256, 0, stream>>>(W, QW);
  cvt_kernel<<<2048, 256, 0, stream>>>(X, XB, MTOT * DIN / 4);
  dim3 grid(MTOT / 256, DOUT / 256);
  gemm256_kernel<<<grid, 512, 0, stream>>>(XB, QW, scale, bias, out);
}

// Round 9
// 223.586 us; speedup vs baseline: 2.9991x; 2.5466x over previous
//
#include <hip/hip_runtime.h>
#include <hip/hip_bf16.h>
#include <stdint.h>

#define DIN   4096
#define DOUT  4096
#define MTOT  8192

#define BK    64
#define NKT   (DIN / BK)   // 64 K-tiles

typedef int i32x4 __attribute__((ext_vector_type(4)));

__device__ __forceinline__ void glds16(const void* g, void* l) {
  __builtin_amdgcn_global_load_lds(
      (__attribute__((address_space(1))) void*)g,
      (__attribute__((address_space(3))) void*)l, 16, 0, 0);
}

// ---------------------------------------------------------------------------
// Kernel 1: per-row alpha (fp64 accumulate) + ternary quantize -> i8 {-1,0,1}
// ---------------------------------------------------------------------------
__global__ __launch_bounds__(256) void quant_w(const float* __restrict__ W,
                                               int8_t* __restrict__ QW) {
  const int row = blockIdx.x;
  const int t = threadIdx.x;
  const float* wr = W + (size_t)row * DIN;

  float4 v[4];
  double s = 0.0;
#pragma unroll
  for (int j = 0; j < 4; ++j) {
    v[j] = reinterpret_cast<const float4*>(wr)[j * 256 + t];
    s += (double)fabsf(v[j].x) + (double)fabsf(v[j].y) +
         (double)fabsf(v[j].z) + (double)fabsf(v[j].w);
  }
#pragma unroll
  for (int off = 32; off > 0; off >>= 1) s += __shfl_down(s, off, 64);

  __shared__ double ssum[4];
  __shared__ float salpha;
  if ((t & 63) == 0) ssum[t >> 6] = s;
  __syncthreads();
  if (t == 0) salpha = (float)((ssum[0] + ssum[1] + ssum[2] + ssum[3]) / (double)DIN);
  __syncthreads();
  const float alpha = salpha;

  int* qo = reinterpret_cast<int*>(QW + (size_t)row * DIN);
#pragma unroll
  for (int j = 0; j < 4; ++j) {
    int q0 = v[j].x > alpha ? 1 : (v[j].x < -alpha ? -1 : 0);
    int q1 = v[j].y > alpha ? 1 : (v[j].y < -alpha ? -1 : 0);
    int q2 = v[j].z > alpha ? 1 : (v[j].z < -alpha ? -1 : 0);
    int q3 = v[j].w > alpha ? 1 : (v[j].w < -alpha ? -1 : 0);
    qo[j * 256 + t] =
        (q0 & 0xff) | ((q1 & 0xff) << 8) | ((q2 & 0xff) << 16) | ((q3 & 0xff) << 24);
  }
}

// ---------------------------------------------------------------------------
// Kernel 2: x fp32 -> i8 with per-row scale. xq = rint(x * 127/rowmax),
// XS[row] = rowmax/127. Quantization err <= rowmax/254 per elem.
// ---------------------------------------------------------------------------
__global__ __launch_bounds__(256) void quant_x(const float* __restrict__ X,
                                               int8_t* __restrict__ XQ,
                                               float* __restrict__ XS) {
  const int row = blockIdx.x;
  const int t = threadIdx.x;
  const float* xr = X + (size_t)row * DIN;

  float4 v[4];
  float mx = 0.f;
#pragma unroll
  for (int j = 0; j < 4; ++j) {
    v[j] = reinterpret_cast<const float4*>(xr)[j * 256 + t];
    mx = fmaxf(mx, fmaxf(fmaxf(fabsf(v[j].x), fabsf(v[j].y)),
                         fmaxf(fabsf(v[j].z), fabsf(v[j].w))));
  }
#pragma unroll
  for (int off = 32; off > 0; off >>= 1) mx = fmaxf(mx, __shfl_down(mx, off, 64));

  __shared__ float smax[4];
  __shared__ float sinv, ssc;
  if ((t & 63) == 0) smax[t >> 6] = mx;
  __syncthreads();
  if (t == 0) {
    float rm = fmaxf(fmaxf(smax[0], smax[1]), fmaxf(smax[2], smax[3]));
    sinv = rm > 0.f ? 127.f / rm : 0.f;
    ssc  = rm > 0.f ? rm / 127.f : 0.f;
  }
  __syncthreads();
  const float inv = sinv;
  if (t == 0) XS[row] = ssc;

  int* qo = reinterpret_cast<int*>(XQ + (size_t)row * DIN);
#pragma unroll
  for (int j = 0; j < 4; ++j) {
    int q0 = (int)rintf(v[j].x * inv);
    int q1 = (int)rintf(v[j].y * inv);
    int q2 = (int)rintf(v[j].z * inv);
    int q3 = (int)rintf(v[j].w * inv);
    qo[j * 256 + t] =
        (q0 & 0xff) | ((q1 & 0xff) << 8) | ((q2 & 0xff) << 16) | ((q3 & 0xff) << 24);
  }
}

// ---------------------------------------------------------------------------
// Kernel 3: 256x256 i8 MFMA GEMM (mfma_i32_16x16x64_i8), r3-proven phase flow.
// out[m][n] = (xq @ qw^T)[m][n] * XS[m] * scale[n] + bias[n]
// 512 thr = 8 waves (2Mx4N), wave owns 128x64; BK=64 consumed by ONE mfma per
// frag pair -> 32 MFMA/wave/tile, ds_reads A:8 B:4 per wave/tile.
// LDS: A/B [256 rows][64B] i8, double-buffered = 64 KB total.
// Swizzle: 16B chunk c' = c ^ ((row>>1)&3) (rows are 64B = 2 banks-rows);
// glds dest linear, source applies the same involution, ds_read applies it.
// Phases (quadrants (0,0),(0,1),(1,1),(1,0)), staging 1 half (1 glds)/phase:
//   ph1: read aA[4]+b0[2]; ISSUE B.h1(T+1); BAR; lgkm0; MMA(0,0); BAR
//   ph2: read b1[2];                        BAR; lgkm0; MMA(0,1); BAR
//   ph3: read aB[4]; ISSUE B.h0(T+2);       BAR; lgkm0; MMA(1,1); BAR
//   ph4: ISSUE A.h0+A.h1(T+2); vmcnt(3|0);  BAR; lgkm0; MMA(1,0); BAR
// Overwrite audit (wave reads both its A-subtiles from ONE staged A half,
// both B-subtiles from ONE staged B half):
//   B.h1(T+1)->Bs[buf^1]@ph1: region last read (T-1).ph1/ph2, drained there.
//   B.h0(T+2)->Bs[buf]@ph3:  b0 drained ph1, b1 drained ph2 (lgkm0 < BAR2).
//   A(T+2)->As[buf]@ph4:     aA drained ph1, aB drained ph3.
// All reads drain at the pre-MMA lgkm0, before that phase's BAR2; every
// overwrite is issued >=1 barrier later.  SAFE.
// vmcnt ledger (per-tile stream: B1(T+1)@ph1, B0(T+2)@ph3, A0,A1(T+2)@ph4):
// tile T+1's last load = B.h1(T+1)@T.ph1; exactly 3 loads trail it at the
// T.ph4 wait -> vmcnt(3) == tile T+1 fully landed. vmcnt(0) for T>=NKT-2.
// ---------------------------------------------------------------------------
__global__ __launch_bounds__(512, 2) void gemm256_i8(
    const int8_t* __restrict__ XQ, const int8_t* __restrict__ QW,
    const float* __restrict__ XS, const float* __restrict__ scale,
    const float* __restrict__ bias, float* __restrict__ out) {
  __shared__ int8_t As[2][16384];  // 16 KB each buf
  __shared__ int8_t Bs[2][16384];

  const int t = threadIdx.x;
  const int lane = t & 63;
  const int wid = t >> 6;
  const int wr = wid >> 2, wc = wid & 3;          // 2x4 wave grid
  const int m0 = blockIdx.x * 256;                // m fast-varying
  const int n0 = blockIdx.y * 256;

  const int8_t* ag = XQ + (size_t)m0 * DIN;
  const int8_t* bg = QW + (size_t)n0 * DIN;

  i32x4 acc[8][4] = {};            // [m-frag 0..7][n-frag 0..3]
  i32x4 aA[4], aB[4];              // A quadrant frags (4 m-frags, full K=64)
  i32x4 b0[2], b1[2];              // B frag pairs nh=0 / nh=1

  const int r = lane & 15, kq = lane >> 4;        // frag row / 16B k-chunk
  const int srow = t >> 2;                        // staging row 0..127
  const int scol = ((t & 3) ^ ((srow >> 1) & 3)) * 16;  // inverse-swizzled src

// issue one half-tile (1 glds16/thread): q: 0=A.h0 1=B.h0 2=A.h1 3=B.h1
#define ISSUE_H(Tt_, q_) do {                                                   \
    const int T_ = (Tt_);                                                       \
    if (T_ < NKT) {                                                             \
      const int q__ = (q_), hf_ = q__ >> 1, bf_ = T_ & 1;                       \
      const int8_t* gb_ = (q__ & 1) ? bg : ag;                                  \
      int8_t* lb_ = (q__ & 1) ? &Bs[bf_][0] : &As[bf_][0];                      \
      glds16(gb_ + (size_t)(hf_ * 128 + srow) * DIN + T_ * 64 + scol,           \
             lb_ + hf_ * 8192 + t * 16);                                        \
    }                                                                           \
  } while (0)

#define READA_TO(dst_, buf_, mh_) do {                                          \
    _Pragma("unroll")                                                           \
    for (int mi = 0; mi < 4; ++mi) {                                            \
      const int row_ = wr * 128 + ((mh_) * 4 + mi) * 16 + r;                    \
      dst_[mi] = *reinterpret_cast<const i32x4*>(                               \
          &As[buf_][row_ * 64 + (kq ^ ((row_ >> 1) & 3)) * 16]);                \
    }                                                                           \
  } while (0)

#define READB_TO(dst_, buf_, nh_) do {                                          \
    _Pragma("unroll")                                                           \
    for (int ni = 0; ni < 2; ++ni) {                                            \
      const int row_ = wc * 64 + ((nh_) * 2 + ni) * 16 + r;                     \
      dst_[ni] = *reinterpret_cast<const i32x4*>(                               \
          &Bs[buf_][row_ * 64 + (kq ^ ((row_ >> 1) & 3)) * 16]);                \
    }                                                                           \
  } while (0)

#define MMA(mh_, nh_, areg_, breg_) do {                                        \
    __builtin_amdgcn_s_setprio(1);                                              \
    _Pragma("unroll")                                                           \
    for (int mi = 0; mi < 4; ++mi) {                                            \
      _Pragma("unroll")                                                         \
      for (int ni = 0; ni < 2; ++ni) {                                          \
        acc[(mh_) * 4 + mi][(nh_) * 2 + ni] =                                   \
            __builtin_amdgcn_mfma_i32_16x16x64_i8(                              \
                areg_[mi], breg_[ni],                                           \
                acc[(mh_) * 4 + mi][(nh_) * 2 + ni], 0, 0, 0);                  \
      }                                                                         \
    }                                                                           \
    __builtin_amdgcn_s_setprio(0);                                              \
  } while (0)

#define BAR() __builtin_amdgcn_s_barrier()
#define LGKM0() asm volatile("s_waitcnt lgkmcnt(0)" ::: "memory")

#define TILE(T_, buf_) do {                                                     \
    /* ph1: (0,0) */                                                            \
    READA_TO(aA, buf_, 0);                                                      \
    READB_TO(b0, buf_, 0);                                                      \
    ISSUE_H((T_) + 1, 3);                                                       \
    BAR(); LGKM0();                                                             \
    MMA(0, 0, aA, b0);                                                          \
    BAR();                                                                      \
    /* ph2: (0,1) */                                                            \
    READB_TO(b1, buf_, 1);                                                      \
    BAR(); LGKM0();                                                             \
    MMA(0, 1, aA, b1);                                                          \
    BAR();                                                                      \
    /* ph3: (1,1) — B(T+2) overwrite legal: b0 drained ph1, b1 ph2 */           \
    READA_TO(aB, buf_, 1);                                                      \
    ISSUE_H((T_) + 2, 1);                                                       \
    BAR(); LGKM0();                                                             \
    MMA(1, 1, aB, b1);                                                          \
    BAR();                                                                      \
    /* ph4: (1,0) — A(T+2) overwrite legal: aA drained ph1, aB ph3 */           \
    ISSUE_H((T_) + 2, 0);                                                       \
    ISSUE_H((T_) + 2, 2);                                                       \
    if ((T_) < NKT - 2)                                                         \
      asm volatile("s_waitcnt vmcnt(3)" ::: "memory");                          \
    else                                                                        \
      asm volatile("s_waitcnt vmcnt(0)" ::: "memory");                          \
    BAR(); LGKM0();                                                             \
    MMA(1, 0, aB, b0);                                                          \
    BAR();                                                                      \
  } while (0)

  // prologue: tile0 all 4 halves, then tile1 A.h0, A.h1, B.h0 (7 loads;
  // B.h1(1) is issued at T0.ph1). vmcnt(3) => tile0's 4 loads landed.
  ISSUE_H(0, 0); ISSUE_H(0, 2); ISSUE_H(0, 1); ISSUE_H(0, 3);
  ISSUE_H(1, 0); ISSUE_H(1, 2); ISSUE_H(1, 1);
  asm volatile("s_waitcnt vmcnt(3)" ::: "memory");
  __builtin_amdgcn_s_barrier();

  for (int T = 0; T < NKT; T += 2) {
    TILE(T, 0);
    TILE(T + 1, 1);
  }

  // epilogue: C/D lane map col=lane&15, row=(lane>>4)*4+e (dtype-independent)
  const int q4 = lane >> 4;
#pragma unroll
  for (int ni = 0; ni < 4; ++ni) {
    const int col = n0 + wc * 64 + ni * 16 + r;
    const float sc = scale[col];
    const float bs = bias[col];
#pragma unroll
    for (int mi = 0; mi < 8; ++mi) {
      const int row = m0 + wr * 128 + mi * 16 + q4 * 4;
#pragma unroll
      for (int e = 0; e < 4; ++e) {
        const float xs = XS[row + e];
        out[(size_t)(row + e) * DOUT + col] =
            (float)acc[mi][ni][e] * (xs * sc) + bs;
      }
    }
  }
#undef ISSUE_H
#undef READA_TO
#undef READB_TO
#undef MMA
#undef BAR
#undef LGKM0
#undef TILE
}

extern "C" void kernel_launch(void* const* d_in, const int* in_sizes, int n_in,
                              void* d_out, int out_size, void* d_ws, size_t ws_size,
                              hipStream_t stream) {
  const float* X     = (const float*)d_in[0];
  const float* W     = (const float*)d_in[1];
  const float* scale = (const float*)d_in[2];
  const float* bias  = (const float*)d_in[3];
  float* out = (float*)d_out;

  // ws layout: QW i8 16 MB | XQ i8 32 MB | XS fp32 32 KB
  int8_t* QW = (int8_t*)d_ws;
  int8_t* XQ = (int8_t*)d_ws + (size_t)DOUT * DIN;
  float*  XS = (float*)((int8_t*)d_ws + (size_t)DOUT * DIN + (size_t)MTOT * DIN);

  quant_w<<<DOUT, 256, 0, stream>>>(W, QW);
  quant_x<<<MTOT, 256, 0, stream>>>(X, XQ, XS);
  dim3 grid(MTOT / 256, DOUT / 256);
  gemm256_i8<<<grid, 512, 0, stream>>>(XQ, QW, XS, scale, bias, out);
}

// Round 10
// 217.612 us; speedup vs baseline: 3.0815x; 1.0275x over previous
//
#include <hip/hip_runtime.h>
#include <hip/hip_bf16.h>
#include <stdint.h>

#define DIN   4096
#define DOUT  4096
#define MTOT  8192

#define BK    64
#define NKT   (DIN / BK)   // 64 K-tiles

typedef int i32x4 __attribute__((ext_vector_type(4)));

__device__ __forceinline__ void glds16(const void* g, void* l) {
  __builtin_amdgcn_global_load_lds(
      (__attribute__((address_space(1))) void*)g,
      (__attribute__((address_space(3))) void*)l, 16, 0, 0);
}

// ---------------------------------------------------------------------------
// Kernel 1: per-row alpha (fp64 accumulate) + ternary quantize -> i8 {-1,0,1}
// ---------------------------------------------------------------------------
__global__ __launch_bounds__(256) void quant_w(const float* __restrict__ W,
                                               int8_t* __restrict__ QW) {
  const int row = blockIdx.x;
  const int t = threadIdx.x;
  const float* wr = W + (size_t)row * DIN;

  float4 v[4];
  double s = 0.0;
#pragma unroll
  for (int j = 0; j < 4; ++j) {
    v[j] = reinterpret_cast<const float4*>(wr)[j * 256 + t];
    s += (double)fabsf(v[j].x) + (double)fabsf(v[j].y) +
         (double)fabsf(v[j].z) + (double)fabsf(v[j].w);
  }
#pragma unroll
  for (int off = 32; off > 0; off >>= 1) s += __shfl_down(s, off, 64);

  __shared__ double ssum[4];
  __shared__ float salpha;
  if ((t & 63) == 0) ssum[t >> 6] = s;
  __syncthreads();
  if (t == 0) salpha = (float)((ssum[0] + ssum[1] + ssum[2] + ssum[3]) / (double)DIN);
  __syncthreads();
  const float alpha = salpha;

  int* qo = reinterpret_cast<int*>(QW + (size_t)row * DIN);
#pragma unroll
  for (int j = 0; j < 4; ++j) {
    int q0 = v[j].x > alpha ? 1 : (v[j].x < -alpha ? -1 : 0);
    int q1 = v[j].y > alpha ? 1 : (v[j].y < -alpha ? -1 : 0);
    int q2 = v[j].z > alpha ? 1 : (v[j].z < -alpha ? -1 : 0);
    int q3 = v[j].w > alpha ? 1 : (v[j].w < -alpha ? -1 : 0);
    qo[j * 256 + t] =
        (q0 & 0xff) | ((q1 & 0xff) << 8) | ((q2 & 0xff) << 16) | ((q3 & 0xff) << 24);
  }
}

// ---------------------------------------------------------------------------
// Kernel 2: x fp32 -> i8 with per-row scale. xq = rint(x * 127/rowmax),
// XS[row] = rowmax/127.
// ---------------------------------------------------------------------------
__global__ __launch_bounds__(256) void quant_x(const float* __restrict__ X,
                                               int8_t* __restrict__ XQ,
                                               float* __restrict__ XS) {
  const int row = blockIdx.x;
  const int t = threadIdx.x;
  const float* xr = X + (size_t)row * DIN;

  float4 v[4];
  float mx = 0.f;
#pragma unroll
  for (int j = 0; j < 4; ++j) {
    v[j] = reinterpret_cast<const float4*>(xr)[j * 256 + t];
    mx = fmaxf(mx, fmaxf(fmaxf(fabsf(v[j].x), fabsf(v[j].y)),
                         fmaxf(fabsf(v[j].z), fabsf(v[j].w))));
  }
#pragma unroll
  for (int off = 32; off > 0; off >>= 1) mx = fmaxf(mx, __shfl_down(mx, off, 64));

  __shared__ float smax[4];
  __shared__ float sinv, ssc;
  if ((t & 63) == 0) smax[t >> 6] = mx;
  __syncthreads();
  if (t == 0) {
    float rm = fmaxf(fmaxf(smax[0], smax[1]), fmaxf(smax[2], smax[3]));
    sinv = rm > 0.f ? 127.f / rm : 0.f;
    ssc  = rm > 0.f ? rm / 127.f : 0.f;
  }
  __syncthreads();
  const float inv = sinv;
  if (t == 0) XS[row] = ssc;

  int* qo = reinterpret_cast<int*>(XQ + (size_t)row * DIN);
#pragma unroll
  for (int j = 0; j < 4; ++j) {
    int q0 = (int)rintf(v[j].x * inv);
    int q1 = (int)rintf(v[j].y * inv);
    int q2 = (int)rintf(v[j].z * inv);
    int q3 = (int)rintf(v[j].w * inv);
    qo[j * 256 + t] =
        (q0 & 0xff) | ((q1 & 0xff) << 8) | ((q2 & 0xff) << 16) | ((q3 & 0xff) << 24);
  }
}

// ---------------------------------------------------------------------------
// Kernel 3: 256x256 i8 MFMA GEMM (mfma_i32_16x16x64_i8), round-10:
// SINGLE barrier per phase (4/tile, was 8) + uniform T+2 staging.
//
// Phase shape: READ(subtile); ISSUE(glds); MMA(consumes this phase's reads);
// BAR.  Overwrite-safety invariant: a glds overwrite of region R is issued
// after a barrier every wave reached after its last read of R completed.
// Reads complete before their consuming MFMA (compiler lgkmcnt), which
// precedes the phase's BAR -> the next phase's ISSUE is safe.
//
//   ph1: read aA[4]+b0[2];                     MMA(0,0); BAR
//   ph2: read b1[2];                           MMA(0,1); BAR
//   ph3: read aB[4]; ISSUE B.h0+B.h1(T+2);     MMA(1,1); BAR
//   ph4: ISSUE A.h0+A.h1(T+2); MMA(1,0); vmcnt(4|0); BAR
//
// Overwrite audit:
//   B(T+2)->Bs[buf]@ph3: b0 read ph1, b1 read ph2; issuer crossed ph2 BAR. OK
//   A(T+2)->As[buf]@ph4: aA read ph1, aB read ph3; issuer crossed ph3 BAR. OK
//   Tile T+1 reads at (T+1).ph1 gated by T.ph4's vmcnt+BAR.               OK
// vmcnt ledger (per-tile stream B0,B1@ph3, A0,A1@ph4): after A1(T+2) is
// issued, exactly the 4 loads of tile T+2 trail everything of tile T+1
// -> vmcnt(4) == tile T+1 fully landed. vmcnt(0) for T >= NKT-2.
// ---------------------------------------------------------------------------
__global__ __launch_bounds__(512, 2) void gemm256_i8(
    const int8_t* __restrict__ XQ, const int8_t* __restrict__ QW,
    const float* __restrict__ XS, const float* __restrict__ scale,
    const float* __restrict__ bias, float* __restrict__ out) {
  __shared__ int8_t As[2][16384];  // 16 KB each buf
  __shared__ int8_t Bs[2][16384];

  const int t = threadIdx.x;
  const int lane = t & 63;
  const int wid = t >> 6;
  const int wr = wid >> 2, wc = wid & 3;          // 2x4 wave grid
  const int m0 = blockIdx.x * 256;                // m fast-varying
  const int n0 = blockIdx.y * 256;

  const int8_t* ag = XQ + (size_t)m0 * DIN;
  const int8_t* bg = QW + (size_t)n0 * DIN;

  i32x4 acc[8][4] = {};            // [m-frag 0..7][n-frag 0..3]
  i32x4 aA[4], aB[4];              // A quadrant frags (4 m-frags, full K=64)
  i32x4 b0[2], b1[2];              // B frag pairs nh=0 / nh=1

  const int r = lane & 15, kq = lane >> 4;        // frag row / 16B k-chunk
  const int srow = t >> 2;                        // staging row 0..127
  const int scol = ((t & 3) ^ ((srow >> 1) & 3)) * 16;  // inverse-swizzled src

// issue one half-tile (1 glds16/thread): q: 0=A.h0 1=B.h0 2=A.h1 3=B.h1
#define ISSUE_H(Tt_, q_) do {                                                   \
    const int T_ = (Tt_);                                                       \
    if (T_ < NKT) {                                                             \
      const int q__ = (q_), hf_ = q__ >> 1, bf_ = T_ & 1;                       \
      const int8_t* gb_ = (q__ & 1) ? bg : ag;                                  \
      int8_t* lb_ = (q__ & 1) ? &Bs[bf_][0] : &As[bf_][0];                      \
      glds16(gb_ + (size_t)(hf_ * 128 + srow) * DIN + T_ * 64 + scol,           \
             lb_ + hf_ * 8192 + t * 16);                                        \
    }                                                                           \
  } while (0)

#define READA_TO(dst_, buf_, mh_) do {                                          \
    _Pragma("unroll")                                                           \
    for (int mi = 0; mi < 4; ++mi) {                                            \
      const int row_ = wr * 128 + ((mh_) * 4 + mi) * 16 + r;                    \
      dst_[mi] = *reinterpret_cast<const i32x4*>(                               \
          &As[buf_][row_ * 64 + (kq ^ ((row_ >> 1) & 3)) * 16]);                \
    }                                                                           \
  } while (0)

#define READB_TO(dst_, buf_, nh_) do {                                          \
    _Pragma("unroll")                                                           \
    for (int ni = 0; ni < 2; ++ni) {                                            \
      const int row_ = wc * 64 + ((nh_) * 2 + ni) * 16 + r;                     \
      dst_[ni] = *reinterpret_cast<const i32x4*>(                               \
          &Bs[buf_][row_ * 64 + (kq ^ ((row_ >> 1) & 3)) * 16]);                \
    }                                                                           \
  } while (0)

#define MMA(mh_, nh_, areg_, breg_) do {                                        \
    __builtin_amdgcn_s_setprio(1);                                              \
    _Pragma("unroll")                                                           \
    for (int mi = 0; mi < 4; ++mi) {                                            \
      _Pragma("unroll")                                                         \
      for (int ni = 0; ni < 2; ++ni) {                                          \
        acc[(mh_) * 4 + mi][(nh_) * 2 + ni] =                                   \
            __builtin_amdgcn_mfma_i32_16x16x64_i8(                              \
                areg_[mi], breg_[ni],                                           \
                acc[(mh_) * 4 + mi][(nh_) * 2 + ni], 0, 0, 0);                  \
      }                                                                         \
    }                                                                           \
    __builtin_amdgcn_s_setprio(0);                                              \
  } while (0)

#define BAR() __builtin_amdgcn_s_barrier()

#define TILE(T_, buf_) do {                                                     \
    /* ph1: (0,0) */                                                            \
    READA_TO(aA, buf_, 0);                                                      \
    READB_TO(b0, buf_, 0);                                                      \
    MMA(0, 0, aA, b0);                                                          \
    BAR();                                                                      \
    /* ph2: (0,1) */                                                            \
    READB_TO(b1, buf_, 1);                                                      \
    MMA(0, 1, aA, b1);                                                          \
    BAR();                                                                      \
    /* ph3: (1,1) — B(T+2) overwrite legal: b0 consumed ph1, b1 ph2 */          \
    READA_TO(aB, buf_, 1);                                                      \
    ISSUE_H((T_) + 2, 1);                                                       \
    ISSUE_H((T_) + 2, 3);                                                       \
    MMA(1, 1, aB, b1);                                                          \
    BAR();                                                                      \
    /* ph4: (1,0) — A(T+2) overwrite legal: aA consumed ph1, aB ph3 */          \
    ISSUE_H((T_) + 2, 0);                                                       \
    ISSUE_H((T_) + 2, 2);                                                       \
    MMA(1, 0, aB, b0);                                                          \
    if ((T_) < NKT - 2)                                                         \
      asm volatile("s_waitcnt vmcnt(4)" ::: "memory");                          \
    else                                                                        \
      asm volatile("s_waitcnt vmcnt(0)" ::: "memory");                          \
    BAR();                                                                      \
  } while (0)

  // prologue: tiles 0 and 1 fully staged, stream order B0,B1,A0,A1 per tile
  // (matches steady state). vmcnt(4) => tile0's 4 loads landed.
  ISSUE_H(0, 1); ISSUE_H(0, 3); ISSUE_H(0, 0); ISSUE_H(0, 2);
  ISSUE_H(1, 1); ISSUE_H(1, 3); ISSUE_H(1, 0); ISSUE_H(1, 2);
  asm volatile("s_waitcnt vmcnt(4)" ::: "memory");
  __builtin_amdgcn_s_barrier();

  for (int T = 0; T < NKT; T += 2) {
    TILE(T, 0);
    TILE(T + 1, 1);
  }

  // epilogue: C/D lane map col=lane&15, row=(lane>>4)*4+e (dtype-independent)
  const int q4 = lane >> 4;
#pragma unroll
  for (int ni = 0; ni < 4; ++ni) {
    const int col = n0 + wc * 64 + ni * 16 + r;
    const float sc = scale[col];
    const float bs = bias[col];
#pragma unroll
    for (int mi = 0; mi < 8; ++mi) {
      const int row = m0 + wr * 128 + mi * 16 + q4 * 4;
#pragma unroll
      for (int e = 0; e < 4; ++e) {
        const float xs = XS[row + e];
        out[(size_t)(row + e) * DOUT + col] =
            (float)acc[mi][ni][e] * (xs * sc) + bs;
      }
    }
  }
#undef ISSUE_H
#undef READA_TO
#undef READB_TO
#undef MMA
#undef BAR
#undef TILE
}

extern "C" void kernel_launch(void* const* d_in, const int* in_sizes, int n_in,
                              void* d_out, int out_size, void* d_ws, size_t ws_size,
                              hipStream_t stream) {
  const float* X     = (const float*)d_in[0];
  const float* W     = (const float*)d_in[1];
  const float* scale = (const float*)d_in[2];
  const float* bias  = (const float*)d_in[3];
  float* out = (float*)d_out;

  // ws layout: QW i8 16 MB | XQ i8 32 MB | XS fp32 32 KB
  int8_t* QW = (int8_t*)d_ws;
  int8_t* XQ = (int8_t*)d_ws + (size_t)DOUT * DIN;
  float*  XS = (float*)((int8_t*)d_ws + (size_t)DOUT * DIN + (size_t)MTOT * DIN);

  quant_w<<<DOUT, 256, 0, stream>>>(W, QW);
  quant_x<<<MTOT, 256, 0, stream>>>(X, XQ, XS);
  dim3 grid(MTOT / 256, DOUT / 256);
  gemm256_i8<<<grid, 512, 0, stream>>>(XQ, QW, XS, scale, bias, out);
}

// Round 11
// 205.902 us; speedup vs baseline: 3.2567x; 1.0569x over previous
//
#include <hip/hip_runtime.h>
#include <hip/hip_bf16.h>
#include <stdint.h>

#define DIN   4096
#define DOUT  4096
#define MTOT  8192

#define BK    64
#define NKT   (DIN / BK)   // 64 K-tiles

typedef int i32x4 __attribute__((ext_vector_type(4)));

__device__ __forceinline__ void glds16(const void* g, void* l) {
  __builtin_amdgcn_global_load_lds(
      (__attribute__((address_space(1))) void*)g,
      (__attribute__((address_space(3))) void*)l, 16, 0, 0);
}

// ---------------------------------------------------------------------------
// Kernel 1: per-row alpha (fp64 accumulate) + ternary quantize -> i8 {-1,0,1}
// ---------------------------------------------------------------------------
__global__ __launch_bounds__(256) void quant_w(const float* __restrict__ W,
                                               int8_t* __restrict__ QW) {
  const int row = blockIdx.x;
  const int t = threadIdx.x;
  const float* wr = W + (size_t)row * DIN;

  float4 v[4];
  double s = 0.0;
#pragma unroll
  for (int j = 0; j < 4; ++j) {
    v[j] = reinterpret_cast<const float4*>(wr)[j * 256 + t];
    s += (double)fabsf(v[j].x) + (double)fabsf(v[j].y) +
         (double)fabsf(v[j].z) + (double)fabsf(v[j].w);
  }
#pragma unroll
  for (int off = 32; off > 0; off >>= 1) s += __shfl_down(s, off, 64);

  __shared__ double ssum[4];
  __shared__ float salpha;
  if ((t & 63) == 0) ssum[t >> 6] = s;
  __syncthreads();
  if (t == 0) salpha = (float)((ssum[0] + ssum[1] + ssum[2] + ssum[3]) / (double)DIN);
  __syncthreads();
  const float alpha = salpha;

  int* qo = reinterpret_cast<int*>(QW + (size_t)row * DIN);
#pragma unroll
  for (int j = 0; j < 4; ++j) {
    int q0 = v[j].x > alpha ? 1 : (v[j].x < -alpha ? -1 : 0);
    int q1 = v[j].y > alpha ? 1 : (v[j].y < -alpha ? -1 : 0);
    int q2 = v[j].z > alpha ? 1 : (v[j].z < -alpha ? -1 : 0);
    int q3 = v[j].w > alpha ? 1 : (v[j].w < -alpha ? -1 : 0);
    qo[j * 256 + t] =
        (q0 & 0xff) | ((q1 & 0xff) << 8) | ((q2 & 0xff) << 16) | ((q3 & 0xff) << 24);
  }
}

// ---------------------------------------------------------------------------
// Kernel 2: x fp32 -> i8 with per-row scale. xq = rint(x * 127/rowmax),
// XS[row] = rowmax/127.
// ---------------------------------------------------------------------------
__global__ __launch_bounds__(256) void quant_x(const float* __restrict__ X,
                                               int8_t* __restrict__ XQ,
                                               float* __restrict__ XS) {
  const int row = blockIdx.x;
  const int t = threadIdx.x;
  const float* xr = X + (size_t)row * DIN;

  float4 v[4];
  float mx = 0.f;
#pragma unroll
  for (int j = 0; j < 4; ++j) {
    v[j] = reinterpret_cast<const float4*>(xr)[j * 256 + t];
    mx = fmaxf(mx, fmaxf(fmaxf(fabsf(v[j].x), fabsf(v[j].y)),
                         fmaxf(fabsf(v[j].z), fabsf(v[j].w))));
  }
#pragma unroll
  for (int off = 32; off > 0; off >>= 1) mx = fmaxf(mx, __shfl_down(mx, off, 64));

  __shared__ float smax[4];
  __shared__ float sinv, ssc;
  if ((t & 63) == 0) smax[t >> 6] = mx;
  __syncthreads();
  if (t == 0) {
    float rm = fmaxf(fmaxf(smax[0], smax[1]), fmaxf(smax[2], smax[3]));
    sinv = rm > 0.f ? 127.f / rm : 0.f;
    ssc  = rm > 0.f ? rm / 127.f : 0.f;
  }
  __syncthreads();
  const float inv = sinv;
  if (t == 0) XS[row] = ssc;

  int* qo = reinterpret_cast<int*>(XQ + (size_t)row * DIN);
#pragma unroll
  for (int j = 0; j < 4; ++j) {
    int q0 = (int)rintf(v[j].x * inv);
    int q1 = (int)rintf(v[j].y * inv);
    int q2 = (int)rintf(v[j].z * inv);
    int q3 = (int)rintf(v[j].w * inv);
    qo[j * 256 + t] =
        (q0 & 0xff) | ((q1 & 0xff) << 8) | ((q2 & 0xff) << 16) | ((q3 & 0xff) << 24);
  }
}

// ---------------------------------------------------------------------------
// Kernel 3: 256x256 i8 MFMA GEMM (mfma_i32_16x16x64_i8), round-11:
// TWO phases per tile (2 barrier windows, 16 MFMA each).
//
//   ph1: read aA[4]+b0[2]+b1[2]; ISSUE A.h0+A.h1(T+1);
//        MMA(0,0)+(0,1) [16]; BAR
//   ph2: read aB[4];             ISSUE B.h0+B.h1(T+2);
//        MMA(1,0)+(1,1) [16]; vmcnt(2|0); BAR
//
// Safety invariant (proven r9/r10): every ds_read is consumed by the SAME
// phase's MFMA (compiler lgkmcnt before MFMA) => complete before that
// phase's BAR; every glds overwrite-issue sits >=1 BAR later.
//   A(T+1)->As[(T+1)&1]@T.ph1: last reads of that buffer were tile (T-1)'s
//     aA@ph1 / aB@ph2, consumed there; issuer crossed (T-1).ph2 BAR.   OK
//   B(T+2)->Bs[T&1]@T.ph2: b0,b1 consumed at T.ph1; issuer crossed
//     T.ph1 BAR.                                                      OK
//   Tile T+1 reads gated by T.ph2's vmcnt+BAR.                        OK
// vmcnt ledger (stream: ...B(T+1)@(T-1).ph2 < A(T+1)@T.ph1 < B(T+2)@T.ph2):
//   at T.ph2 wait, only B(T+2)'s 2 loads trail A(T+1) -> vmcnt(2) ==
//   A(T+1) and B(T+1) fully landed. vmcnt(0) for T >= NKT-2 (B(NKT) not
//   issued, so counted wait would not cover A(NKT-1)).
// ---------------------------------------------------------------------------
__global__ __launch_bounds__(512, 2) void gemm256_i8(
    const int8_t* __restrict__ XQ, const int8_t* __restrict__ QW,
    const float* __restrict__ XS, const float* __restrict__ scale,
    const float* __restrict__ bias, float* __restrict__ out) {
  __shared__ int8_t As[2][16384];  // 16 KB each buf
  __shared__ int8_t Bs[2][16384];

  const int t = threadIdx.x;
  const int lane = t & 63;
  const int wid = t >> 6;
  const int wr = wid >> 2, wc = wid & 3;          // 2x4 wave grid
  const int m0 = blockIdx.x * 256;                // m fast-varying
  const int n0 = blockIdx.y * 256;

  const int8_t* ag = XQ + (size_t)m0 * DIN;
  const int8_t* bg = QW + (size_t)n0 * DIN;

  i32x4 acc[8][4] = {};            // [m-frag 0..7][n-frag 0..3]
  i32x4 aA[4], aB[4];              // A quadrant frags (4 m-frags, full K=64)
  i32x4 b0[2], b1[2];              // B frag pairs nh=0 / nh=1

  const int r = lane & 15, kq = lane >> 4;        // frag row / 16B k-chunk
  const int srow = t >> 2;                        // staging row 0..127
  const int scol = ((t & 3) ^ ((srow >> 1) & 3)) * 16;  // inverse-swizzled src

// issue one half-tile (1 glds16/thread): q: 0=A.h0 1=B.h0 2=A.h1 3=B.h1
#define ISSUE_H(Tt_, q_) do {                                                   \
    const int T_ = (Tt_);                                                       \
    if (T_ < NKT) {                                                             \
      const int q__ = (q_), hf_ = q__ >> 1, bf_ = T_ & 1;                       \
      const int8_t* gb_ = (q__ & 1) ? bg : ag;                                  \
      int8_t* lb_ = (q__ & 1) ? &Bs[bf_][0] : &As[bf_][0];                      \
      glds16(gb_ + (size_t)(hf_ * 128 + srow) * DIN + T_ * 64 + scol,           \
             lb_ + hf_ * 8192 + t * 16);                                        \
    }                                                                           \
  } while (0)

#define READA_TO(dst_, buf_, mh_) do {                                          \
    _Pragma("unroll")                                                           \
    for (int mi = 0; mi < 4; ++mi) {                                            \
      const int row_ = wr * 128 + ((mh_) * 4 + mi) * 16 + r;                    \
      dst_[mi] = *reinterpret_cast<const i32x4*>(                               \
          &As[buf_][row_ * 64 + (kq ^ ((row_ >> 1) & 3)) * 16]);                \
    }                                                                           \
  } while (0)

#define READB_TO(dst_, buf_, nh_) do {                                          \
    _Pragma("unroll")                                                           \
    for (int ni = 0; ni < 2; ++ni) {                                            \
      const int row_ = wc * 64 + ((nh_) * 2 + ni) * 16 + r;                     \
      dst_[ni] = *reinterpret_cast<const i32x4*>(                               \
          &Bs[buf_][row_ * 64 + (kq ^ ((row_ >> 1) & 3)) * 16]);                \
    }                                                                           \
  } while (0)

// one output-row-half (mh) x full N: (mh,0)+(mh,1) = 16 MFMA in one cluster
#define MMA2(mh_, areg_) do {                                                   \
    __builtin_amdgcn_s_setprio(1);                                              \
    _Pragma("unroll")                                                           \
    for (int mi = 0; mi < 4; ++mi) {                                            \
      _Pragma("unroll")                                                         \
      for (int ni = 0; ni < 2; ++ni) {                                          \
        acc[(mh_) * 4 + mi][ni] =                                               \
            __builtin_amdgcn_mfma_i32_16x16x64_i8(                              \
                areg_[mi], b0[ni], acc[(mh_) * 4 + mi][ni], 0, 0, 0);           \
        acc[(mh_) * 4 + mi][2 + ni] =                                           \
            __builtin_amdgcn_mfma_i32_16x16x64_i8(                              \
                areg_[mi], b1[ni], acc[(mh_) * 4 + mi][2 + ni], 0, 0, 0);       \
      }                                                                         \
    }                                                                           \
    __builtin_amdgcn_s_setprio(0);                                              \
  } while (0)

#define BAR() __builtin_amdgcn_s_barrier()

#define TILE(T_, buf_) do {                                                     \
    /* ph1 — A(T+1) overwrite legal: tile T-1 consumed As[buf^1] by its ph2 */  \
    READA_TO(aA, buf_, 0);                                                      \
    READB_TO(b0, buf_, 0);                                                      \
    READB_TO(b1, buf_, 1);                                                      \
    ISSUE_H((T_) + 1, 0);                                                       \
    ISSUE_H((T_) + 1, 2);                                                       \
    MMA2(0, aA);                                                                \
    BAR();                                                                      \
    /* ph2 — B(T+2) overwrite legal: b0,b1 consumed ph1 */                      \
    READA_TO(aB, buf_, 1);                                                      \
    ISSUE_H((T_) + 2, 1);                                                       \
    ISSUE_H((T_) + 2, 3);                                                       \
    MMA2(1, aB);                                                                \
    if ((T_) < NKT - 2)                                                         \
      asm volatile("s_waitcnt vmcnt(2)" ::: "memory");                          \
    else                                                                        \
      asm volatile("s_waitcnt vmcnt(0)" ::: "memory");                          \
    BAR();                                                                      \
  } while (0)

  // prologue: A(0) + B(0) + B(1), 6 loads, stream order matches steady state.
  // vmcnt(2) => A(0),B(0) landed (B(1)'s 2 loads may remain in flight).
  ISSUE_H(0, 0); ISSUE_H(0, 2); ISSUE_H(0, 1); ISSUE_H(0, 3);
  ISSUE_H(1, 1); ISSUE_H(1, 3);
  asm volatile("s_waitcnt vmcnt(2)" ::: "memory");
  __builtin_amdgcn_s_barrier();

  for (int T = 0; T < NKT; T += 2) {
    TILE(T, 0);
    TILE(T + 1, 1);
  }

  // epilogue: C/D lane map col=lane&15, row=(lane>>4)*4+e (dtype-independent)
  const int q4 = lane >> 4;
#pragma unroll
  for (int ni = 0; ni < 4; ++ni) {
    const int col = n0 + wc * 64 + ni * 16 + r;
    const float sc = scale[col];
    const float bs = bias[col];
#pragma unroll
    for (int mi = 0; mi < 8; ++mi) {
      const int row = m0 + wr * 128 + mi * 16 + q4 * 4;
#pragma unroll
      for (int e = 0; e < 4; ++e) {
        const float xs = XS[row + e];
        out[(size_t)(row + e) * DOUT + col] =
            (float)acc[mi][ni][e] * (xs * sc) + bs;
      }
    }
  }
#undef ISSUE_H
#undef READA_TO
#undef READB_TO
#undef MMA2
#undef BAR
#undef TILE
}

extern "C" void kernel_launch(void* const* d_in, const int* in_sizes, int n_in,
                              void* d_out, int out_size, void* d_ws, size_t ws_size,
                              hipStream_t stream) {
  const float* X     = (const float*)d_in[0];
  const float* W     = (const float*)d_in[1];
  const float* scale = (const float*)d_in[2];
  const float* bias  = (const float*)d_in[3];
  float* out = (float*)d_out;

  // ws layout: QW i8 16 MB | XQ i8 32 MB | XS fp32 32 KB
  int8_t* QW = (int8_t*)d_ws;
  int8_t* XQ = (int8_t*)d_ws + (size_t)DOUT * DIN;
  float*  XS = (float*)((int8_t*)d_ws + (size_t)DOUT * DIN + (size_t)MTOT * DIN);

  quant_w<<<DOUT, 256, 0, stream>>>(W, QW);
  quant_x<<<MTOT, 256, 0, stream>>>(X, XQ, XS);
  dim3 grid(MTOT / 256, DOUT / 256);
  gemm256_i8<<<grid, 512, 0, stream>>>(XQ, QW, XS, scale, bias, out);
}